// Round 13
// baseline (296.738 us; speedup 1.0000x reference)
//
#include <hip/hip_runtime.h>
#include <hip/hip_bf16.h>

typedef unsigned short u16;
typedef __bf16 bf16x8 __attribute__((ext_vector_type(8)));
typedef float f32x4 __attribute__((ext_vector_type(4)));

// Problem constants (B=4, S=2048, D=4096, E=8, r=8)
constexpr int Mdim = 8192;   // B*S
constexpr int Ndim = 4096;   // D (output features)
constexpr int Kdim = 4096;   // D (input features)
constexpr int ER   = 64;     // E*r
constexpr float LSCALE = 2.0f;  // alpha/r = 16/8

// round-to-nearest-even fp32 -> bf16 (finite inputs)
__device__ __forceinline__ u16 f2bf(float f) {
    union { float f; unsigned u; } v; v.f = f;
    unsigned r = v.u + 0x7fffu + ((v.u >> 16) & 1u);
    return (u16)(r >> 16);
}

#define GLOAD_LDS16(g, l)                                             \
    __builtin_amdgcn_global_load_lds(                                 \
        (const __attribute__((address_space(1))) void*)(g),           \
        (__attribute__((address_space(3))) void*)(l), 16, 0, 0)

// ---------------------------------------------------------------------------
// Fused pre-pass: cvt_x (16384 logical blocks) + weff (2048 logical blocks),
// interleaved 8:1 so both run concurrently (bx%9==8 -> weff).
// ---------------------------------------------------------------------------
__global__ __launch_bounds__(256) void fused_pre_kernel(
    const float* __restrict__ x, const float* __restrict__ W,
    const float* __restrict__ A, const float* __restrict__ Bm,
    u16* __restrict__ Xb, u16* __restrict__ Wb)
{
    __shared__ __align__(16) float sAc[ER][128];
    __shared__ __align__(16) float sBc[64][ER];

    const int bx = blockIdx.x;
    const int t  = threadIdx.x;

    if ((bx % 9) != 8) {
        const int ci = (bx / 9) * 8 + (bx % 9);      // 0..16383
        const size_t i = ((size_t)ci * 256 + t) * 8;
        const float4 v0 = *(const float4*)(x + i);
        const float4 v1 = *(const float4*)(x + i + 4);
        uint4 o;
        o.x = (unsigned)f2bf(v0.x) | ((unsigned)f2bf(v0.y) << 16);
        o.y = (unsigned)f2bf(v0.z) | ((unsigned)f2bf(v0.w) << 16);
        o.z = (unsigned)f2bf(v1.x) | ((unsigned)f2bf(v1.y) << 16);
        o.w = (unsigned)f2bf(v1.z) | ((unsigned)f2bf(v1.w) << 16);
        *(uint4*)(Xb + i) = o;
        return;
    }

    const int w  = bx / 9;                           // 0..2047
    const int i0 = (w & 31) * 128;
    const int o0 = (w >> 5) * 64;

#pragma unroll
    for (int p = 0; p < 8; ++p) {
        int lin = p * 1024 + t * 4;
        int er = lin >> 7, ci2 = lin & 127;
        *(float4*)&sAc[er][ci2] = *(const float4*)(A + (size_t)er * Kdim + i0 + ci2);
    }
    {
        int ol = t >> 2;
        int c  = (t & 3) * 16;
#pragma unroll
        for (int q = 0; q < 2; ++q) {
            int er = c + q * 8;
            int e  = er >> 3;
            const float* src = Bm + ((size_t)e * Ndim + (o0 + ol)) * 8;
            *(float4*)&sBc[ol][er]     = *(const float4*)(src);
            *(float4*)&sBc[ol][er + 4] = *(const float4*)(src + 4);
        }
    }
    __syncthreads();

    const int tx = t & 31;
    const int ty = t >> 5;
    float acc[8][4] = {};
#pragma unroll 4
    for (int er = 0; er < ER; ++er) {
        float4 a = *(const float4*)&sAc[er][tx * 4];
#pragma unroll
        for (int q = 0; q < 8; ++q) {
            float bv = sBc[q * 8 + ty][er];
            acc[q][0] += bv * a.x;
            acc[q][1] += bv * a.y;
            acc[q][2] += bv * a.z;
            acc[q][3] += bv * a.w;
        }
    }
#pragma unroll
    for (int q = 0; q < 8; ++q) {
        int o = o0 + q * 8 + ty;
        const float4 wv4 = *(const float4*)(W + (size_t)o * Kdim + i0 + tx * 4);
        ushort4 st;
        st.x = f2bf(wv4.x + LSCALE * acc[q][0]);
        st.y = f2bf(wv4.y + LSCALE * acc[q][1]);
        st.z = f2bf(wv4.z + LSCALE * acc[q][2]);
        st.w = f2bf(wv4.w + LSCALE * acc[q][3]);
        *(ushort4*)(Wb + (size_t)o * Kdim + i0 + tx * 4) = st;
    }
}

// ---------------------------------------------------------------------------
// GEMM: 256x256x64, 8-phase schedule with B-HELD registers (round-13).
// vs r12: every phase issues exactly 8 ds_read_b128 (template's "4 or 8"),
// B (4 n-frags x 2kk = 32 VGPR) is read once per K-tile at P1 and held;
// parity arrays BP/BQ carry prev tile's B for the deferred Q(1,0).
// Phase map per tile T (E in buf0):
//   P1: DS_B(T, all) -> BP | STG | BAR;LGKM0; MQ(1,0)[afB(T-1) x BQ] ;BAR
//   P2: DS_A(T,mh0)->afA  | STG | BAR;LGKM0; MQ(0,0)[afA x BP]      ;BAR
//   P3: DS_A(T,mh1)->afB  | STG | BAR;LGKM0; MQ(0,1)[afA x BP]      ;BAR
//   P4: (no DS)           | STG;VM6 | BAR;  MQ(1,1)[afB x BP]       ;BAR
// Staging skeleton identical to r12: P1:O:A1, P2:E2:B0, P3:E2:B1, P4:E2:A0
// +vmcnt6, P5:E2:A1, P6:O2:B0, P7:O2:B1, P8:O2:A0 +vmcnt6 (never 0 in loop).
// Slot-overwrite invariants (race-free, >=1 barrier after last read):
//   B0,B1 last read P1 (all waves) -> staged P2/P3 OK (fixes r12's P2 race);
//   A0,A1 last read P3 -> staged P4/P5 OK; buf1 slots symmetric.
// vmcnt(6)@P4: newest 6 = E2:{B0,B1,A0} -> O fully landed before P5. @P8 sym.
// Swizzle (r4-r6, 0 conflicts): stored chunk = global chunk ^ (row&7) via
// pre-swizzled source; reads XOR same key. 8 waves 2Mx4N, 128x64/wave.
// ---------------------------------------------------------------------------
constexpr int BM = 256, BN = 256, BK = 64;

__global__ __launch_bounds__(512, 2) void gemm_bias_kernel(
    const u16* __restrict__ Xb, const u16* __restrict__ Wb,
    const float* __restrict__ bias, float* __restrict__ C)
{
    __shared__ __align__(16) u16 lds[65536];   // 128 KiB

    const int t    = threadIdx.x;
    const int lane = t & 63;
    const int wv   = t >> 6;
    const int wr   = wv >> 2;   // 0..1
    const int wc   = wv & 3;    // 0..3

    const int wg  = blockIdx.x;
    const int xcd = wg & 7, lid = wg >> 3;
    const int mt  = (xcd & 1) * 16 + (lid >> 2);   // 0..31
    const int ntl = (xcd >> 1) * 4 + (lid & 3);    // 0..15
    const int bm  = mt * BM;
    const int bn  = ntl * BN;

    u16* buf0 = lds;            // slots (u16): A0 +0, A1 +8192, B0 +16384, B1 +24576
    u16* buf1 = lds + 32768;

    const int rl  = t >> 3;                          // 0..63 row low
    const int scl = ((t ^ (t >> 3)) & 7) * 8;        // pre-swizzled col (u16)
    const u16* aSrc0 = Xb + (size_t)(bm + rl) * Kdim + scl;
    const u16* aSrc1 = Xb + (size_t)(bm + 128 + rl) * Kdim + scl;
    const u16* bSrc0 = Wb + (size_t)(bn + rl) * Kdim + scl;
    const u16* bSrc1 = Wb + (size_t)(bn + 128 + rl) * Kdim + scl;
    constexpr size_t R64 = (size_t)64 * Kdim;

#define STG(BUF, SLOT, SRCP, KO)                                              \
    do {                                                                      \
        GLOAD_LDS16((SRCP) + (KO), (BUF) + (SLOT) + t * 8);                   \
        GLOAD_LDS16((SRCP) + (KO) + R64, (BUF) + (SLOT) + 4096 + t * 8);      \
    } while (0)

    const int fr  = lane & 15;
    const int cp0 = (((lane >> 4) ^ (lane & 7)) & 7) * 8;          // kk=0
    const int cp1 = ((((lane >> 4) + 4) ^ (lane & 7)) & 7) * 8;    // kk=1
    const int aB  = wr * 8192;
    const int bB  = 16384 + (wc >> 1) * 8192 + (wc & 1) * 4096;

    f32x4 acc[8][4];
#pragma unroll
    for (int i = 0; i < 8; ++i)
#pragma unroll
        for (int j = 0; j < 4; ++j)
            acc[i][j] = f32x4{0.f, 0.f, 0.f, 0.f};

    bf16x8 af[4][2];      // A frags of one m-half (afA role)
    bf16x8 ah[4][2];      // A frags held m-half (afB role, crosses tile bdry)
    bf16x8 bP[4][2];      // B frags of current tile (all 4 n-frags)
    bf16x8 bQ[4][2];      // B frags of previous tile

#define DS_A(BUF, MH, AR)                                                     \
    _Pragma("unroll")                                                         \
    for (int mi = 0; mi < 4; ++mi) {                                          \
        const int rb = aB + ((MH) * 64 + mi * 16 + fr) * 64;                  \
        AR[mi][0] = *(const bf16x8*)&(BUF)[rb + cp0];                         \
        AR[mi][1] = *(const bf16x8*)&(BUF)[rb + cp1];                         \
    }

#define DS_B(BUF, BR)                                                         \
    _Pragma("unroll")                                                         \
    for (int ni = 0; ni < 4; ++ni) {                                          \
        const int rb = bB + (ni * 16 + fr) * 64;                              \
        BR[ni][0] = *(const bf16x8*)&(BUF)[rb + cp0];                         \
        BR[ni][1] = *(const bf16x8*)&(BUF)[rb + cp1];                         \
    }

#define MQ(AR, BR, MH, NH)                                                    \
    __builtin_amdgcn_s_setprio(1);                                            \
    _Pragma("unroll")                                                         \
    for (int mi = 0; mi < 4; ++mi)                                            \
        _Pragma("unroll")                                                     \
        for (int ni = 0; ni < 2; ++ni) {                                      \
            acc[(MH)*4 + mi][(NH)*2 + ni] =                                   \
                __builtin_amdgcn_mfma_f32_16x16x32_bf16(                      \
                    AR[mi][0], BR[(NH)*2 + ni][0],                            \
                    acc[(MH)*4 + mi][(NH)*2 + ni], 0, 0, 0);                  \
            acc[(MH)*4 + mi][(NH)*2 + ni] =                                   \
                __builtin_amdgcn_mfma_f32_16x16x32_bf16(                      \
                    AR[mi][1], BR[(NH)*2 + ni][1],                            \
                    acc[(MH)*4 + mi][(NH)*2 + ni], 0, 0, 0);                  \
        }                                                                     \
    __builtin_amdgcn_s_setprio(0);

#define FENCE asm volatile("" ::: "memory")
#define BAR   __builtin_amdgcn_s_barrier(); FENCE
#define LGKM0 asm volatile("s_waitcnt lgkmcnt(0)" ::: "memory");              \
              __builtin_amdgcn_sched_barrier(0)
#define VM6   asm volatile("s_waitcnt vmcnt(6)" ::: "memory")

    // prologue: stage E0 {B0,B1,A0,A1} + O1 {B0,B1,A0}; land E0; sync.
    STG(buf0, 16384, bSrc0, 0);
    STG(buf0, 24576, bSrc1, 0);
    STG(buf0, 0,     aSrc0, 0);
    STG(buf0, 8192,  aSrc1, 0);
    STG(buf1, 16384, bSrc0, 64);
    STG(buf1, 24576, bSrc1, 64);
    STG(buf1, 0,     aSrc0, 64);
    VM6;
    BAR;

    // FIRST=1 handled by predicating P1's MQ on g||half (first E tile only).
#pragma unroll 1
    for (int g = 0; g < 32; ++g) {
        const int koO  = (2 * g + 1) * 64;
        const int koE2 = ((2 * g + 2) & 63) * 64;
        const int koO2 = ((2 * g + 3) & 63) * 64;

        // ---- tile E (buf0) ----
        // P1
        DS_B(buf0, bP);
        STG(buf1, 8192, aSrc1, koO);          // O:A1
        BAR; LGKM0;
        if (g != 0) { MQ(ah, bQ, 1, 0); }     // Q(1,0) of prev O
        BAR;
        // P2
        DS_A(buf0, 0, af);
        STG(buf0, 16384, bSrc0, koE2);        // E+2:B0
        BAR; LGKM0; MQ(af, bP, 0, 0); BAR;
        // P3
        DS_A(buf0, 1, ah);
        STG(buf0, 24576, bSrc1, koE2);        // E+2:B1
        BAR; LGKM0; MQ(af, bP, 0, 1); BAR;
        // P4
        STG(buf0, 0, aSrc0, koE2);            // E+2:A0
        VM6;
        BAR; MQ(ah, bP, 1, 1); BAR;

        // ---- tile O (buf1) ----
        // P5
        DS_B(buf1, bQ);
        STG(buf0, 8192, aSrc1, koE2);         // E+2:A1
        BAR; LGKM0; MQ(ah, bP, 1, 0); BAR;    // Q(1,0) of E
        // P6
        DS_A(buf1, 0, af);
        STG(buf1, 16384, bSrc0, koO2);        // O+2:B0
        BAR; LGKM0; MQ(af, bQ, 0, 0); BAR;
        // P7
        DS_A(buf1, 1, ah);
        STG(buf1, 24576, bSrc1, koO2);        // O+2:B1
        BAR; LGKM0; MQ(af, bQ, 0, 1); BAR;
        // P8
        STG(buf1, 0, aSrc0, koO2);            // O+2:A0
        VM6;
        BAR; MQ(ah, bQ, 1, 1); BAR;
    }
    MQ(ah, bQ, 1, 0);                         // drain Q(1,0) of final O

#undef STG
#undef DS_A
#undef DS_B
#undef MQ

    // epilogue: bias add + store (C/D layout: col=lane&15, row=(lane>>4)*4+j)
#pragma unroll
    for (int ni = 0; ni < 4; ++ni) {
        const int col = bn + wc * 64 + ni * 16 + (lane & 15);
        const float bv = bias[col];
#pragma unroll
        for (int mi = 0; mi < 8; ++mi) {
            const int rbase = bm + wr * 128 + mi * 16 + (lane >> 4) * 4;
#pragma unroll
            for (int j = 0; j < 4; ++j)
                C[(size_t)(rbase + j) * Ndim + col] = acc[mi][ni][j] + bv;
        }
    }
}

// ---------------------------------------------------------------------------
// Fallback (only if ws too small): slow but correct fp32 row-per-block kernel
// ---------------------------------------------------------------------------
__global__ __launch_bounds__(256) void naive_row_kernel(
    const float* __restrict__ x, const float* __restrict__ W,
    const float* __restrict__ bias, const float* __restrict__ A,
    const float* __restrict__ Bm, float* __restrict__ out)
{
    __shared__ float sx[Kdim];
    __shared__ float st[ER];
    const int m = blockIdx.x;
    const float* xr = x + (size_t)m * Kdim;
    for (int i = threadIdx.x; i < Kdim; i += 256) sx[i] = xr[i];
    __syncthreads();
    if (threadIdx.x < ER) {
        const float* ar = A + (size_t)threadIdx.x * Kdim;
        float s = 0.f;
        for (int i = 0; i < Kdim; ++i) s += sx[i] * ar[i];
        st[threadIdx.x] = s;
    }
    __syncthreads();
    for (int o = threadIdx.x; o < Ndim; o += 256) {
        const float* wr = W + (size_t)o * Kdim;
        float s = bias[o];
        for (int i = 0; i < Kdim; ++i) s += sx[i] * wr[i];
        float l = 0.f;
        for (int e = 0; e < 8; ++e) {
            const float* bp = Bm + ((size_t)e * Ndim + o) * 8;
            for (int r = 0; r < 8; ++r) l += st[e * 8 + r] * bp[r];
        }
        out[(size_t)m * Ndim + o] = s + LSCALE * l;
    }
}

extern "C" void kernel_launch(void* const* d_in, const int* in_sizes, int n_in,
                              void* d_out, int out_size, void* d_ws, size_t ws_size,
                              hipStream_t stream)
{
    const float* x  = (const float*)d_in[0];
    const float* W  = (const float*)d_in[1];
    const float* b  = (const float*)d_in[2];
    const float* A  = (const float*)d_in[3];
    const float* Bm = (const float*)d_in[4];
    float* out = (float*)d_out;

    const size_t xb_bytes = (size_t)Mdim * Kdim * 2;   // 64 MB
    const size_t wb_bytes = (size_t)Ndim * Kdim * 2;   // 32 MB

    if (ws_size >= xb_bytes + wb_bytes) {
        u16* Xb = (u16*)d_ws;
        u16* Wb = (u16*)((char*)d_ws + xb_bytes);
        fused_pre_kernel<<<18432, 256, 0, stream>>>(x, W, A, Bm, Xb, Wb);
        gemm_bias_kernel<<<dim3((Mdim / BM) * (Ndim / BN)), 512, 0, stream>>>(Xb, Wb, b, out);
    } else {
        naive_row_kernel<<<Mdim, 256, 0, stream>>>(x, W, b, A, Bm, out);
    }
}

// Round 14
// 280.445 us; speedup vs baseline: 1.0581x; 1.0581x over previous
//
#include <hip/hip_runtime.h>
#include <hip/hip_bf16.h>

typedef unsigned short u16;
typedef __bf16 bf16x8 __attribute__((ext_vector_type(8)));
typedef float f32x4 __attribute__((ext_vector_type(4)));

// Problem constants (B=4, S=2048, D=4096, E=8, r=8)
constexpr int Mdim = 8192;   // B*S
constexpr int Ndim = 4096;   // D (output features)
constexpr int Kdim = 4096;   // D (input features)
constexpr int ER   = 64;     // E*r
constexpr float LSCALE = 2.0f;  // alpha/r = 16/8

// round-to-nearest-even fp32 -> bf16 (finite inputs)
__device__ __forceinline__ u16 f2bf(float f) {
    union { float f; unsigned u; } v; v.f = f;
    unsigned r = v.u + 0x7fffu + ((v.u >> 16) & 1u);
    return (u16)(r >> 16);
}

#define GLOAD_LDS16(g, l)                                             \
    __builtin_amdgcn_global_load_lds(                                 \
        (const __attribute__((address_space(1))) void*)(g),           \
        (__attribute__((address_space(3))) void*)(l), 16, 0, 0)

// ---------------------------------------------------------------------------
// Fused pre-pass (measured ~42-45 us, at its HBM roofline): cvt_x (16384
// logical blocks) + weff (2048 logical blocks), interleaved 8:1.
//   cvt: Xb[i] = bf16(x[i]), 8 elems/thread.
//   weff: Wb[o,i] = bf16(W[o,i] + SCALE * sum_er Bcat[o,er]*Acat[er,i]).
// ---------------------------------------------------------------------------
__global__ __launch_bounds__(256) void fused_pre_kernel(
    const float* __restrict__ x, const float* __restrict__ W,
    const float* __restrict__ A, const float* __restrict__ Bm,
    u16* __restrict__ Xb, u16* __restrict__ Wb)
{
    __shared__ __align__(16) float sAc[ER][128];
    __shared__ __align__(16) float sBc[64][ER];

    const int bx = blockIdx.x;
    const int t  = threadIdx.x;

    if ((bx % 9) != 8) {
        const int ci = (bx / 9) * 8 + (bx % 9);      // 0..16383
        const size_t i = ((size_t)ci * 256 + t) * 8;
        const float4 v0 = *(const float4*)(x + i);
        const float4 v1 = *(const float4*)(x + i + 4);
        uint4 o;
        o.x = (unsigned)f2bf(v0.x) | ((unsigned)f2bf(v0.y) << 16);
        o.y = (unsigned)f2bf(v0.z) | ((unsigned)f2bf(v0.w) << 16);
        o.z = (unsigned)f2bf(v1.x) | ((unsigned)f2bf(v1.y) << 16);
        o.w = (unsigned)f2bf(v1.z) | ((unsigned)f2bf(v1.w) << 16);
        *(uint4*)(Xb + i) = o;
        return;
    }

    const int w  = bx / 9;                           // 0..2047
    const int i0 = (w & 31) * 128;
    const int o0 = (w >> 5) * 64;

#pragma unroll
    for (int p = 0; p < 8; ++p) {
        int lin = p * 1024 + t * 4;
        int er = lin >> 7, ci2 = lin & 127;
        *(float4*)&sAc[er][ci2] = *(const float4*)(A + (size_t)er * Kdim + i0 + ci2);
    }
    {
        int ol = t >> 2;
        int c  = (t & 3) * 16;
#pragma unroll
        for (int q = 0; q < 2; ++q) {
            int er = c + q * 8;
            int e  = er >> 3;
            const float* src = Bm + ((size_t)e * Ndim + (o0 + ol)) * 8;
            *(float4*)&sBc[ol][er]     = *(const float4*)(src);
            *(float4*)&sBc[ol][er + 4] = *(const float4*)(src + 4);
        }
    }
    __syncthreads();

    const int tx = t & 31;
    const int ty = t >> 5;
    float acc[8][4] = {};
#pragma unroll 4
    for (int er = 0; er < ER; ++er) {
        float4 a = *(const float4*)&sAc[er][tx * 4];
#pragma unroll
        for (int q = 0; q < 8; ++q) {
            float bv = sBc[q * 8 + ty][er];
            acc[q][0] += bv * a.x;
            acc[q][1] += bv * a.y;
            acc[q][2] += bv * a.z;
            acc[q][3] += bv * a.w;
        }
    }
#pragma unroll
    for (int q = 0; q < 8; ++q) {
        int o = o0 + q * 8 + ty;
        const float4 wv4 = *(const float4*)(W + (size_t)o * Kdim + i0 + tx * 4);
        ushort4 st;
        st.x = f2bf(wv4.x + LSCALE * acc[q][0]);
        st.y = f2bf(wv4.y + LSCALE * acc[q][1]);
        st.z = f2bf(wv4.z + LSCALE * acc[q][2]);
        st.w = f2bf(wv4.w + LSCALE * acc[q][3]);
        *(ushort4*)(Wb + (size_t)o * Kdim + i0 + tx * 4) = st;
    }
}

// ---------------------------------------------------------------------------
// GEMM (round-6 configuration VERBATIM -- the measured best: 230.0 us,
// MfmaUtil 54.7%, 0 bank conflicts). 256x256x64, ONE barrier per K-tile;
// waves drift within the tile so MFMA and LDS pipes overlap across waves.
// Held-back quadrant Q10 of tile T runs at tile T+1's top. 8 waves (2Mx4N),
// per-wave out 128x64 = acc[8][4] f32x4. LDS 128 KiB double-buffered.
// Full XOR swizzle (chunk ^= row&7) on both sides; bank conflicts = 0.
// Frozen after 8 structural variants (r4-r13) all landed 230-300 us:
// this is the family's measured ceiling on this harness.
// ---------------------------------------------------------------------------
constexpr int BM = 256, BN = 256, BK = 64;
constexpr int NT = Kdim / BK;  // 64

__global__ __launch_bounds__(512, 2) void gemm_bias_kernel(
    const u16* __restrict__ Xb, const u16* __restrict__ Wb,
    const float* __restrict__ bias, float* __restrict__ C)
{
    __shared__ __align__(16) u16 lds[65536];   // 128 KiB

    const int t    = threadIdx.x;
    const int lane = t & 63;
    const int wv   = t >> 6;
    const int wr   = wv >> 2;   // 0..1
    const int wc   = wv & 3;    // 0..3

    // XCD-aware swizzle: 512 blocks = 8 XCDs x 64; each XCD owns a 16x4 region
    const int wg  = blockIdx.x;
    const int xcd = wg & 7, lid = wg >> 3;
    const int mt  = (xcd & 1) * 16 + (lid >> 2);   // 0..31
    const int ntl = (xcd >> 1) * 4 + (lid & 3);    // 0..15
    const int bm  = mt * BM;
    const int bn  = ntl * BN;

    u16* b0 = lds;            // buf0: A at [0,16384), B at [16384,32768)
    u16* b1 = lds + 32768;    // buf1

    // --- staging: 8 x global_load_lds(16B) per thread per K-tile ---
    const u16* gSrc[8]; int dOff[8];
#pragma unroll
    for (int i = 0; i < 8; ++i) {
        const int sub = i & 3;
        const int isB = i >> 2;
        const int c   = sub * 512 + t;                    // 0..2047
        const int row = c >> 3;                           // 0..255
        const int scl = ((c ^ row) & 7) * 8;              // swizzled col (u16)
        gSrc[i] = (isB ? Wb + (size_t)(bn + row) * Kdim
                       : Xb + (size_t)(bm + row) * Kdim) + scl;
        dOff[i] = isB * 16384 + c * 8;
    }

    // --- fragment ds_read addressing (swizzled) ---
    const int fr  = lane & 15;                               // row-in-16
    const int cp0 = (((lane >> 4)    ) ^ (lane & 7)) * 8;    // kk=0 chunk col
    const int cp1 = (((lane >> 4) + 4) ^ (lane & 7)) * 8;    // kk=1 chunk col

    f32x4 acc[8][4];
#pragma unroll
    for (int i = 0; i < 8; ++i)
#pragma unroll
        for (int j = 0; j < 4; ++j)
            acc[i][j] = f32x4{0.f, 0.f, 0.f, 0.f};

    bf16x8 af[4][2];    // A fragments for the current m-half (mh0 or mh1)
    bf16x8 bfr[4][2];   // all four B n-fragments

#define DS_AF(BUF, MH)                                                        \
    _Pragma("unroll")                                                         \
    for (int mi = 0; mi < 4; ++mi) {                                          \
        const int rb = (wr * 128 + (MH) * 64 + mi * 16 + fr) * 64;            \
        af[mi][0] = *(const bf16x8*)&(BUF)[rb + cp0];                         \
        af[mi][1] = *(const bf16x8*)&(BUF)[rb + cp1];                         \
    }

#define DS_BF(BUF, NH)                                                        \
    _Pragma("unroll")                                                         \
    for (int nl = 0; nl < 2; ++nl) {                                          \
        const int ni = (NH) * 2 + nl;                                         \
        const int rb = 16384 + (wc * 64 + ni * 16 + fr) * 64;                 \
        bfr[ni][0] = *(const bf16x8*)&(BUF)[rb + cp0];                        \
        bfr[ni][1] = *(const bf16x8*)&(BUF)[rb + cp1];                        \
    }

#define MQ(MH, NH)                                                            \
    __builtin_amdgcn_s_setprio(1);                                            \
    _Pragma("unroll")                                                         \
    for (int mi = 0; mi < 4; ++mi)                                            \
        _Pragma("unroll")                                                     \
        for (int nl = 0; nl < 2; ++nl) {                                      \
            const int ni = (NH) * 2 + nl;                                     \
            acc[(MH)*4 + mi][ni] = __builtin_amdgcn_mfma_f32_16x16x32_bf16(   \
                af[mi][0], bfr[ni][0], acc[(MH)*4 + mi][ni], 0, 0, 0);        \
            acc[(MH)*4 + mi][ni] = __builtin_amdgcn_mfma_f32_16x16x32_bf16(   \
                af[mi][1], bfr[ni][1], acc[(MH)*4 + mi][ni], 0, 0, 0);        \
        }                                                                     \
    __builtin_amdgcn_s_setprio(0);

#define FENCE asm volatile("" ::: "memory")
#define BAR   __builtin_amdgcn_s_barrier(); FENCE

    // TILE(T): ONE barrier. vmcnt(0): tile T's gloads (issued in T-1) landed
    // (T+1's not yet issued); lgkmcnt(0) drains this wave's held-quadrant
    // reads so post-barrier gloads may overwrite that buffer. Body: held
    // MQ10(T-1) [register-only, precedes DS_AF0/DS_BF0 which overwrite its
    // operands], gloads(T+1) into NXT, 24 ds_reads of CUR interleaved with
    // the 4 MFMA quadrants (compiler emits counted lgkmcnt). No mid-tile
    // barriers: waves drift; MFMA of one wave overlaps DS of another.
#define TILE(CUR, NXT, FIRST, LAST)                                           \
    {                                                                         \
        asm volatile("s_waitcnt vmcnt(0) lgkmcnt(0)" ::: "memory");           \
        BAR;                                                                  \
        if (!(FIRST)) { MQ(1, 0); }                                           \
        if (!(LAST)) {                                                        \
            _Pragma("unroll")                                                 \
            for (int i = 0; i < 8; ++i)                                       \
                GLOAD_LDS16(gSrc[i] + koff, (NXT) + dOff[i]);                 \
            koff += 64;                                                       \
        }                                                                     \
        DS_AF(CUR, 0);                                                        \
        DS_BF(CUR, 0);                                                        \
        MQ(0, 0);                                                             \
        DS_BF(CUR, 1);                                                        \
        MQ(0, 1);                                                             \
        DS_AF(CUR, 1);                                                        \
        MQ(1, 1);                                                             \
    }

    // prologue: issue tile 0 into buf0
#pragma unroll
    for (int i = 0; i < 8; ++i) GLOAD_LDS16(gSrc[i], b0 + dOff[i]);

    int koff = 64;   // k element-offset of the next tile to issue (tile 1)

    TILE(b0, b1, 1, 0);                 // T0
#pragma unroll 1
    for (int t2 = 0; t2 < (NT - 2) / 2; ++t2) {   // T1..T62 (31 pairs)
        TILE(b1, b0, 0, 0);
        TILE(b0, b1, 0, 0);
    }
    TILE(b1, b0, 0, 1);                 // T63 (no prefetch)
    MQ(1, 0);                           // drain held Q10 of T63

#undef TILE
#undef MQ
#undef DS_BF
#undef DS_AF

    // epilogue: bias add + store (C/D layout: col=lane&15, row=(lane>>4)*4+j)
#pragma unroll
    for (int ni = 0; ni < 4; ++ni) {
        const int col = bn + wc * 64 + ni * 16 + (lane & 15);
        const float bv = bias[col];
#pragma unroll
        for (int mi = 0; mi < 8; ++mi) {
            const int rbase = bm + wr * 128 + mi * 16 + (lane >> 4) * 4;
#pragma unroll
            for (int j = 0; j < 4; ++j)
                C[(size_t)(rbase + j) * Ndim + col] = acc[mi][ni][j] + bv;
        }
    }
}

// ---------------------------------------------------------------------------
// Fallback (only if ws too small): slow but correct fp32 row-per-block kernel
// ---------------------------------------------------------------------------
__global__ __launch_bounds__(256) void naive_row_kernel(
    const float* __restrict__ x, const float* __restrict__ W,
    const float* __restrict__ bias, const float* __restrict__ A,
    const float* __restrict__ Bm, float* __restrict__ out)
{
    __shared__ float sx[Kdim];
    __shared__ float st[ER];
    const int m = blockIdx.x;
    const float* xr = x + (size_t)m * Kdim;
    for (int i = threadIdx.x; i < Kdim; i += 256) sx[i] = xr[i];
    __syncthreads();
    if (threadIdx.x < ER) {
        const float* ar = A + (size_t)threadIdx.x * Kdim;
        float s = 0.f;
        for (int i = 0; i < Kdim; ++i) s += sx[i] * ar[i];
        st[threadIdx.x] = s;
    }
    __syncthreads();
    for (int o = threadIdx.x; o < Ndim; o += 256) {
        const float* wr = W + (size_t)o * Kdim;
        float s = bias[o];
        for (int i = 0; i < Kdim; ++i) s += sx[i] * wr[i];
        float l = 0.f;
        for (int e = 0; e < 8; ++e) {
            const float* bp = Bm + ((size_t)e * Ndim + o) * 8;
            for (int r = 0; r < 8; ++r) l += st[e * 8 + r] * bp[r];
        }
        out[(size_t)m * Ndim + o] = s + LSCALE * l;
    }
}

extern "C" void kernel_launch(void* const* d_in, const int* in_sizes, int n_in,
                              void* d_out, int out_size, void* d_ws, size_t ws_size,
                              hipStream_t stream)
{
    const float* x  = (const float*)d_in[0];
    const float* W  = (const float*)d_in[1];
    const float* b  = (const float*)d_in[2];
    const float* A  = (const float*)d_in[3];
    const float* Bm = (const float*)d_in[4];
    float* out = (float*)d_out;

    const size_t xb_bytes = (size_t)Mdim * Kdim * 2;   // 64 MB
    const size_t wb_bytes = (size_t)Ndim * Kdim * 2;   // 32 MB

    if (ws_size >= xb_bytes + wb_bytes) {
        u16* Xb = (u16*)d_ws;
        u16* Wb = (u16*)((char*)d_ws + xb_bytes);
        fused_pre_kernel<<<18432, 256, 0, stream>>>(x, W, A, Bm, Xb, Wb);
        gemm_bias_kernel<<<dim3((Mdim / BM) * (Ndim / BN)), 512, 0, stream>>>(Xb, Wb, b, out);
    } else {
        naive_row_kernel<<<Mdim, 256, 0, stream>>>(x, W, b, A, Bm, out);
    }
}